// Round 1
// baseline (1649.553 us; speedup 1.0000x reference)
//
#include <hip/hip_runtime.h>
#include <math.h>

#define DMODEL 1024
#define NQKV   3072
#define SEQ    1024
#define NH     16
#define DH     64
#define HS     (SEQ*DH)          // 65536 per (bt,head)
constexpr float PI_F = 3.14159265358979323846f;

// ---------------------------------------------------------------------------
// GEMM1: qkv = X(8192x1024) @ Wqkv(1024x3072), fused axial RoPE on q,k,
// scatter into q/k/v workspaces laid out [bt][head][s][dim].
// 128x128 tile, BK=16, 256 threads, 8x8 per thread.
// ---------------------------------------------------------------------------
__global__ __launch_bounds__(256) void gemm_qkv_rope(
    const float* __restrict__ X, const float* __restrict__ Wq,
    float* __restrict__ qw, float* __restrict__ kw, float* __restrict__ vw)
{
    __shared__ float As[16][128];   // transposed A tile: As[k][m]
    __shared__ float Bs[16][128];
    const int bx = blockIdx.x;      // n tile 0..23
    const int by = blockIdx.y;      // m tile 0..63
    const int tid = threadIdx.x;
    const int tx = tid & 15, ty = tid >> 4;
    const int ar = tid >> 1;        // A-load row 0..127
    const int ak = (tid & 1) * 8;   // A-load k offset
    const int brow = tid >> 4;      // B-load row 0..15
    const int bcol = (tid & 15) * 8;

    const float* Ap = X + (size_t)(by*128 + ar)*DMODEL + ak;
    const float* Bp = Wq + (size_t)brow*NQKV + bx*128 + bcol;

    float acc[8][8];
#pragma unroll
    for (int i = 0; i < 8; ++i)
#pragma unroll
        for (int j = 0; j < 8; ++j) acc[i][j] = 0.f;

    for (int k0 = 0; k0 < DMODEL; k0 += 16) {
        float4 a0 = *(const float4*)(Ap + k0);
        float4 a1 = *(const float4*)(Ap + k0 + 4);
        float4 b0 = *(const float4*)(Bp + (size_t)k0*NQKV);
        float4 b1 = *(const float4*)(Bp + (size_t)k0*NQKV + 4);
        __syncthreads();
        As[ak+0][ar] = a0.x; As[ak+1][ar] = a0.y; As[ak+2][ar] = a0.z; As[ak+3][ar] = a0.w;
        As[ak+4][ar] = a1.x; As[ak+5][ar] = a1.y; As[ak+6][ar] = a1.z; As[ak+7][ar] = a1.w;
        *(float4*)&Bs[brow][bcol]   = b0;
        *(float4*)&Bs[brow][bcol+4] = b1;
        __syncthreads();
#pragma unroll
        for (int kk = 0; kk < 16; ++kk) {
            float av[8], bv[8];
            *(float4*)&av[0] = *(float4*)&As[kk][ty*8];
            *(float4*)&av[4] = *(float4*)&As[kk][ty*8+4];
            *(float4*)&bv[0] = *(float4*)&Bs[kk][tx*8];
            *(float4*)&bv[4] = *(float4*)&Bs[kk][tx*8+4];
#pragma unroll
            for (int i = 0; i < 8; ++i)
#pragma unroll
                for (int j = 0; j < 8; ++j)
                    acc[i][j] += av[i]*bv[j];
        }
    }

    // epilogue: 8 aligned consecutive cols per thread -> same tensor t, same head
    const int cbase = bx*128 + tx*8;
    const int t    = cbase >> 10;
    const int rem  = cbase & 1023;
    const int head = rem >> 6;
    const int dim0 = rem & 63;
    float* outb = (t == 0) ? qw : ((t == 1) ? kw : vw);
#pragma unroll
    for (int i = 0; i < 8; ++i) {
        int r  = by*128 + ty*8 + i;
        int bt = r >> 10;
        int s  = r & 1023;
        float vals[8];
#pragma unroll
        for (int j = 0; j < 8; ++j) vals[j] = acc[i][j];
        if (t < 2) {
            // axial RoPE: pair pg<16 uses H position, else W position
            int hp = s >> 5, wp = s & 31;
            float ph = -1.0f + hp*(2.0f/31.0f);
            float pw = -1.0f + wp*(2.0f/31.0f);
#pragma unroll
            for (int p = 0; p < 4; ++p) {
                int pg = (dim0 >> 1) + p;          // global pair index 0..31
                float pos = (pg < 16) ? ph : pw;
                int   gi  = (pg < 16) ? pg : (pg - 16);
                float th  = pos * ((1.0f + gi*(127.0f/15.0f)) * PI_F);
                float sn, cs;
                sincosf(th, &sn, &cs);
                float x1 = vals[2*p], x2 = vals[2*p+1];
                vals[2*p]   = x1*cs - x2*sn;
                vals[2*p+1] = x2*cs + x1*sn;
            }
        }
        float* dst = outb + (size_t)(bt*NH + head)*HS + (size_t)s*DH + dim0;
        *(float4*)dst     = *(float4*)&vals[0];
        *(float4*)(dst+4) = *(float4*)&vals[4];
    }
}

// ---------------------------------------------------------------------------
// Flash attention: one block = one (bt,head) x 64-query chunk. Bc=32.
// ---------------------------------------------------------------------------
__global__ __launch_bounds__(256) void attn_kernel(
    const float* __restrict__ qw, const float* __restrict__ kw,
    const float* __restrict__ vw, float* __restrict__ ow)
{
    const int qc = blockIdx.x;   // 0..15 query chunk
    const int bh = blockIdx.y;   // 0..127 (bt*16+head)
    const float* qp = qw + (size_t)bh*HS + qc*64*DH;
    const float* kp = kw + (size_t)bh*HS;
    const float* vp = vw + (size_t)bh*HS;
    float*       op = ow + (size_t)bh*HS + qc*64*DH;

    __shared__ float Qs[64][68];   // pad 68 -> rows shift banks by 4
    __shared__ float Ks[32][68];
    __shared__ float Vs[32][68];
    __shared__ float Ss[64][36];
    __shared__ float ms[64], ls[64], als[64];
    __shared__ float red[256];

    const int tid = threadIdx.x;
    const int tx = tid & 15, ty = tid >> 4;
    const int r0 = ty*4, c0 = tx*2, d0 = tx*4;
    const int rr = tid >> 2, sg = (tid & 3) << 3;

    for (int idx = tid; idx < 64*16; idx += 256) {
        int r = idx >> 4, c4 = (idx & 15) << 2;
        *(float4*)&Qs[r][c4] = *(const float4*)(qp + r*DH + c4);
    }
    if (tid < 64) { ms[tid] = -INFINITY; ls[tid] = 0.f; }
    float oacc[4][4];
#pragma unroll
    for (int i = 0; i < 4; ++i)
#pragma unroll
        for (int d = 0; d < 4; ++d) oacc[i][d] = 0.f;

    for (int kc = 0; kc < 32; ++kc) {
        __syncthreads();   // prev PV done before K/V overwrite
        for (int idx = tid; idx < 32*16; idx += 256) {
            int r = idx >> 4, c4 = (idx & 15) << 2;
            *(float4*)&Ks[r][c4] = *(const float4*)(kp + (size_t)(kc*32 + r)*DH + c4);
            *(float4*)&Vs[r][c4] = *(const float4*)(vp + (size_t)(kc*32 + r)*DH + c4);
        }
        __syncthreads();
        // S = Q K^T * scale ; thread: rows r0..r0+3, cols c0,c0+1
        float sa[4][2];
#pragma unroll
        for (int i = 0; i < 4; ++i) { sa[i][0] = 0.f; sa[i][1] = 0.f; }
#pragma unroll
        for (int d = 0; d < DH; d += 4) {
            float4 k0 = *(float4*)&Ks[c0][d];
            float4 k1 = *(float4*)&Ks[c0+1][d];
#pragma unroll
            for (int i = 0; i < 4; ++i) {
                float4 q = *(float4*)&Qs[r0+i][d];
                sa[i][0] += q.x*k0.x + q.y*k0.y + q.z*k0.z + q.w*k0.w;
                sa[i][1] += q.x*k1.x + q.y*k1.y + q.z*k1.z + q.w*k1.w;
            }
        }
#pragma unroll
        for (int i = 0; i < 4; ++i) {
            Ss[r0+i][c0]   = sa[i][0]*0.125f;
            Ss[r0+i][c0+1] = sa[i][1]*0.125f;
        }
        __syncthreads();
        // stage 1: partial row max (4 threads per row, 8 cols each)
        {
            float mx = -INFINITY;
#pragma unroll
            for (int j = 0; j < 8; ++j) mx = fmaxf(mx, Ss[rr][sg+j]);
            red[tid] = mx;
        }
        __syncthreads();
        // stage 2: finalize max, alpha
        if (tid < 64) {
            float mx = fmaxf(fmaxf(red[tid*4], red[tid*4+1]),
                             fmaxf(red[tid*4+2], red[tid*4+3]));
            float mo = ms[tid];
            float mn = fmaxf(mo, mx);
            als[tid] = expf(mo - mn);    // 0 on first chunk
            ms[tid]  = mn;
        }
        __syncthreads();
        // stage 3: exponentiate + partial sums (all 256 threads)
        {
            float mn = ms[rr];
            float ps = 0.f;
#pragma unroll
            for (int j = 0; j < 8; ++j) {
                float p = expf(Ss[rr][sg+j] - mn);
                Ss[rr][sg+j] = p;
                ps += p;
            }
            red[tid] = ps;
        }
        __syncthreads();
        if (tid < 64)
            ls[tid] = ls[tid]*als[tid] + red[tid*4]+red[tid*4+1]+red[tid*4+2]+red[tid*4+3];
        // PV: thread rows r0..r0+3, dims d0..d0+3
#pragma unroll
        for (int i = 0; i < 4; ++i) {
            float al = als[r0+i];
#pragma unroll
            for (int d = 0; d < 4; ++d) oacc[i][d] *= al;
        }
#pragma unroll
        for (int j = 0; j < 32; j += 4) {
            float4 v0 = *(float4*)&Vs[j+0][d0];
            float4 v1 = *(float4*)&Vs[j+1][d0];
            float4 v2 = *(float4*)&Vs[j+2][d0];
            float4 v3 = *(float4*)&Vs[j+3][d0];
#pragma unroll
            for (int i = 0; i < 4; ++i) {
                float4 p = *(float4*)&Ss[r0+i][j];
                oacc[i][0] += p.x*v0.x + p.y*v1.x + p.z*v2.x + p.w*v3.x;
                oacc[i][1] += p.x*v0.y + p.y*v1.y + p.z*v2.y + p.w*v3.y;
                oacc[i][2] += p.x*v0.z + p.y*v1.z + p.z*v2.z + p.w*v3.z;
                oacc[i][3] += p.x*v0.w + p.y*v1.w + p.z*v2.w + p.w*v3.w;
            }
        }
    }
    __syncthreads();  // ls final
#pragma unroll
    for (int i = 0; i < 4; ++i) {
        float inv = 1.0f / ls[r0+i];
        float4 o4;
        o4.x = oacc[i][0]*inv; o4.y = oacc[i][1]*inv;
        o4.z = oacc[i][2]*inv; o4.w = oacc[i][3]*inv;
        *(float4*)(op + (size_t)(r0+i)*DH + d0) = o4;
    }
}

// ---------------------------------------------------------------------------
// GEMM2: out = o(8192x1024, gathered from [bt][head][s][dim]) @ Wout + bout
// ---------------------------------------------------------------------------
__global__ __launch_bounds__(256) void gemm_out(
    const float* __restrict__ ow, const float* __restrict__ Wo,
    const float* __restrict__ bo, float* __restrict__ out)
{
    __shared__ float As[16][128];
    __shared__ float Bs[16][128];
    const int bx = blockIdx.x;   // 0..7
    const int by = blockIdx.y;   // 0..63
    const int tid = threadIdx.x;
    const int tx = tid & 15, ty = tid >> 4;
    const int ar = tid >> 1;
    const int ak = (tid & 1) * 8;
    const int brow = tid >> 4;
    const int bcol = (tid & 15) * 8;

    const int r  = by*128 + ar;
    const int bt = r >> 10, s = r & 1023;
    const float* Abase = ow + (size_t)bt*NH*HS + (size_t)s*DH;
    const float* Bp = Wo + (size_t)brow*DMODEL + bx*128 + bcol;

    float acc[8][8];
#pragma unroll
    for (int i = 0; i < 8; ++i)
#pragma unroll
        for (int j = 0; j < 8; ++j) acc[i][j] = 0.f;

    for (int k0 = 0; k0 < DMODEL; k0 += 16) {
        int k = k0 + ak;                        // 8-aligned, stays in one head block
        const float* ap = Abase + (size_t)(k >> 6)*HS + (k & 63);
        float4 a0 = *(const float4*)ap;
        float4 a1 = *(const float4*)(ap + 4);
        float4 b0 = *(const float4*)(Bp + (size_t)k0*DMODEL);
        float4 b1 = *(const float4*)(Bp + (size_t)k0*DMODEL + 4);
        __syncthreads();
        As[ak+0][ar] = a0.x; As[ak+1][ar] = a0.y; As[ak+2][ar] = a0.z; As[ak+3][ar] = a0.w;
        As[ak+4][ar] = a1.x; As[ak+5][ar] = a1.y; As[ak+6][ar] = a1.z; As[ak+7][ar] = a1.w;
        *(float4*)&Bs[brow][bcol]   = b0;
        *(float4*)&Bs[brow][bcol+4] = b1;
        __syncthreads();
#pragma unroll
        for (int kk = 0; kk < 16; ++kk) {
            float av[8], bv[8];
            *(float4*)&av[0] = *(float4*)&As[kk][ty*8];
            *(float4*)&av[4] = *(float4*)&As[kk][ty*8+4];
            *(float4*)&bv[0] = *(float4*)&Bs[kk][tx*8];
            *(float4*)&bv[4] = *(float4*)&Bs[kk][tx*8+4];
#pragma unroll
            for (int i = 0; i < 8; ++i)
#pragma unroll
                for (int j = 0; j < 8; ++j)
                    acc[i][j] += av[i]*bv[j];
        }
    }

    const int cb = bx*128 + tx*8;
    float4 bias0 = *(const float4*)(bo + cb);
    float4 bias1 = *(const float4*)(bo + cb + 4);
#pragma unroll
    for (int i = 0; i < 8; ++i) {
        int row = by*128 + ty*8 + i;
        float4 o0, o1;
        o0.x = acc[i][0] + bias0.x; o0.y = acc[i][1] + bias0.y;
        o0.z = acc[i][2] + bias0.z; o0.w = acc[i][3] + bias0.w;
        o1.x = acc[i][4] + bias1.x; o1.y = acc[i][5] + bias1.y;
        o1.z = acc[i][6] + bias1.z; o1.w = acc[i][7] + bias1.w;
        float* dst = out + (size_t)row*DMODEL + cb;
        *(float4*)dst     = o0;
        *(float4*)(dst+4) = o1;
    }
}

// ---------------------------------------------------------------------------
extern "C" void kernel_launch(void* const* d_in, const int* in_sizes, int n_in,
                              void* d_out, int out_size, void* d_ws, size_t ws_size,
                              hipStream_t stream)
{
    const float* x    = (const float*)d_in[0];
    const float* Wqkv = (const float*)d_in[1];
    const float* Wout = (const float*)d_in[2];
    const float* bout = (const float*)d_in[3];
    float* out = (float*)d_out;

    float* ws = (float*)d_ws;
    float* qw = ws;                       // 8*16*1024*64 = 8388608 floats
    float* kw = ws + 8388608;
    float* vw = ws + 16777216;
    float* ow = ws + 25165824;            // total 33554432 floats = 128 MiB

    hipLaunchKernelGGL(gemm_qkv_rope, dim3(24, 64), dim3(256), 0, stream,
                       x, Wqkv, qw, kw, vw);
    hipLaunchKernelGGL(attn_kernel, dim3(16, 128), dim3(256), 0, stream,
                       qw, kw, vw, ow);
    hipLaunchKernelGGL(gemm_out, dim3(8, 64), dim3(256), 0, stream,
                       ow, Wout, bout, out);
}

// Round 2
// 976.547 us; speedup vs baseline: 1.6892x; 1.6892x over previous
//
#include <hip/hip_runtime.h>
#include <math.h>

#define DMODEL 1024
#define NQKV   3072
#define SEQ    1024
#define NH     16
#define DH     64
#define HS     (SEQ*DH)          // 65536 elements per (bt,head)
constexpr float PI_F   = 3.14159265358979323846f;
constexpr float LOG2E  = 1.44269504088896f;

typedef _Float16 half8  __attribute__((ext_vector_type(8)));
typedef float    floatx4 __attribute__((ext_vector_type(4)));

// ---------------------------------------------------------------------------
// GEMM1: qkv = X(8192x1024) @ Wqkv(1024x3072), fused axial RoPE on q,k.
// Emits f16: qw [bh][s][64] (pre-scaled by 1/8), kw [bh][s][64],
//            vt [bh][d][1024] (transposed for PV B-fragments).
// ---------------------------------------------------------------------------
__global__ __launch_bounds__(256) void gemm_qkv_rope(
    const float* __restrict__ X, const float* __restrict__ Wq,
    _Float16* __restrict__ qw, _Float16* __restrict__ kw,
    _Float16* __restrict__ vt)
{
    __shared__ float As[16][128];   // transposed A tile: As[k][m]
    __shared__ float Bs[16][128];
    const int bx = blockIdx.x;      // n tile 0..23
    const int by = blockIdx.y;      // m tile 0..63
    const int tid = threadIdx.x;
    const int tx = tid & 15, ty = tid >> 4;
    const int ar = tid >> 1;        // A-load row 0..127
    const int ak = (tid & 1) * 8;   // A-load k offset
    const int brow = tid >> 4;      // B-load row 0..15
    const int bcol = (tid & 15) * 8;

    const float* Ap = X + (size_t)(by*128 + ar)*DMODEL + ak;
    const float* Bp = Wq + (size_t)brow*NQKV + bx*128 + bcol;

    float acc[8][8];
#pragma unroll
    for (int i = 0; i < 8; ++i)
#pragma unroll
        for (int j = 0; j < 8; ++j) acc[i][j] = 0.f;

    for (int k0 = 0; k0 < DMODEL; k0 += 16) {
        float4 a0 = *(const float4*)(Ap + k0);
        float4 a1 = *(const float4*)(Ap + k0 + 4);
        float4 b0 = *(const float4*)(Bp + (size_t)k0*NQKV);
        float4 b1 = *(const float4*)(Bp + (size_t)k0*NQKV + 4);
        __syncthreads();
        As[ak+0][ar] = a0.x; As[ak+1][ar] = a0.y; As[ak+2][ar] = a0.z; As[ak+3][ar] = a0.w;
        As[ak+4][ar] = a1.x; As[ak+5][ar] = a1.y; As[ak+6][ar] = a1.z; As[ak+7][ar] = a1.w;
        *(float4*)&Bs[brow][bcol]   = b0;
        *(float4*)&Bs[brow][bcol+4] = b1;
        __syncthreads();
#pragma unroll
        for (int kk = 0; kk < 16; ++kk) {
            float av[8], bv[8];
            *(float4*)&av[0] = *(float4*)&As[kk][ty*8];
            *(float4*)&av[4] = *(float4*)&As[kk][ty*8+4];
            *(float4*)&bv[0] = *(float4*)&Bs[kk][tx*8];
            *(float4*)&bv[4] = *(float4*)&Bs[kk][tx*8+4];
#pragma unroll
            for (int i = 0; i < 8; ++i)
#pragma unroll
                for (int j = 0; j < 8; ++j)
                    acc[i][j] += av[i]*bv[j];
        }
    }

    // epilogue: 8 aligned consecutive cols per thread -> same tensor t, same head
    const int cbase = bx*128 + tx*8;
    const int t    = cbase >> 10;
    const int rem  = cbase & 1023;
    const int head = rem >> 6;
    const int dim0 = rem & 63;
    const int r0g  = by*128 + ty*8;       // 8 consecutive global rows, same bt
    const int bt   = r0g >> 10;
    const int s0   = r0g & 1023;
    const int bh   = bt*NH + head;

    if (t < 2) {
        _Float16* outb = (t == 0) ? qw : kw;
        const float scale = (t == 0) ? 0.125f : 1.0f;
#pragma unroll
        for (int i = 0; i < 8; ++i) {
            int s = s0 + i;
            float vals[8];
#pragma unroll
            for (int j = 0; j < 8; ++j) vals[j] = acc[i][j];
            // axial RoPE: pair pg<16 uses H position, else W position
            int hp = s >> 5, wp = s & 31;
            float ph = -1.0f + hp*(2.0f/31.0f);
            float pw = -1.0f + wp*(2.0f/31.0f);
#pragma unroll
            for (int p = 0; p < 4; ++p) {
                int pg = (dim0 >> 1) + p;          // global pair index 0..31
                float pos = (pg < 16) ? ph : pw;
                int   gi  = (pg < 16) ? pg : (pg - 16);
                float th  = pos * ((1.0f + gi*(127.0f/15.0f)) * PI_F);
                float sn, cs;
                sincosf(th, &sn, &cs);
                float x1 = vals[2*p], x2 = vals[2*p+1];
                vals[2*p]   = x1*cs - x2*sn;
                vals[2*p+1] = x2*cs + x1*sn;
            }
            half8 hv;
#pragma unroll
            for (int j = 0; j < 8; ++j) hv[j] = (_Float16)(vals[j]*scale);
            *(half8*)(outb + (size_t)bh*HS + (size_t)s*DH + dim0) = hv;
        }
    } else {
        // v: transpose 8x8 in registers, write vt[bh][d][s0..s0+7]
#pragma unroll
        for (int j = 0; j < 8; ++j) {
            int d = dim0 + j;
            half8 hv;
#pragma unroll
            for (int i = 0; i < 8; ++i) hv[i] = (_Float16)acc[i][j];
            *(half8*)(vt + (size_t)bh*HS + (size_t)d*SEQ + s0) = hv;
        }
    }
}

// ---------------------------------------------------------------------------
// Flash attention, f16 MFMA. Block = 4 waves = one (bt,head) x 64-query tile.
// Wave w owns queries w*16..w*16+15. BC=64 keys per chunk, 16 chunks.
// A-frag: A[m=lane&15][k=quad*8+j]; B-frag: B[k=quad*8+j][n=lane&15];
// C/D:    [row=quad*4+reg][col=lane&15]   (m89/m120 verified layouts)
// ---------------------------------------------------------------------------
#define BQ  64
#define BC  64
#define LDH 72          // padded LDS row stride (halfwords): 144B = 36 dw -> conflict-free

__global__ __launch_bounds__(256) void attn_mfma(
    const _Float16* __restrict__ qw, const _Float16* __restrict__ kw,
    const _Float16* __restrict__ vt, float* __restrict__ ow)
{
    const int qc = blockIdx.x;    // 0..15 query chunk
    const int bh = blockIdx.y;    // 0..127
    const _Float16* qp = qw + (size_t)bh*HS + qc*BQ*DH;
    const _Float16* kp = kw + (size_t)bh*HS;
    const _Float16* vp = vt + (size_t)bh*HS;      // [d][1024]
    float* op = ow + (size_t)bh*HS + qc*BQ*DH;

    __shared__ _Float16 Qs[BQ][LDH];
    __shared__ _Float16 Ks[BC][LDH];
    __shared__ _Float16 Vs[DH][LDH];              // Vt chunk: [d][key]
    __shared__ _Float16 Ps[4][16][LDH];           // per-wave P tile [q][key]

    const int tid  = threadIdx.x;
    const int w    = tid >> 6;
    const int lane = tid & 63;
    const int quad = lane >> 4;
    const int l    = lane & 15;

    // stage Q tile (64 rows x 128B), coalesced
    for (int idx = tid; idx < BQ*8; idx += 256) {
        int r = idx >> 3, c = (idx & 7)*8;
        *(half8*)&Qs[r][c] = *(const half8*)(qp + (size_t)r*DH + c);
    }
    __syncthreads();
    half8 qf0 = *(half8*)&Qs[w*16 + l][quad*8];
    half8 qf1 = *(half8*)&Qs[w*16 + l][quad*8 + 32];

    floatx4 Of[4];
    float mrow[4], lrow[4];
#pragma unroll
    for (int dt = 0; dt < 4; ++dt)
#pragma unroll
        for (int r = 0; r < 4; ++r) Of[dt][r] = 0.f;
#pragma unroll
    for (int r = 0; r < 4; ++r) { mrow[r] = -INFINITY; lrow[r] = 0.f; }

    for (int kc = 0; kc < SEQ/BC; ++kc) {
        __syncthreads();   // prior PV reads of Ks/Vs complete
        for (int idx = tid; idx < BC*8; idx += 256) {
            int r = idx >> 3, c = (idx & 7)*8;
            *(half8*)&Ks[r][c] = *(const half8*)(kp + (size_t)(kc*BC + r)*DH + c);
        }
        for (int idx = tid; idx < DH*8; idx += 256) {
            int r = idx >> 3, c = (idx & 7)*8;
            *(half8*)&Vs[r][c] = *(const half8*)(vp + (size_t)r*SEQ + kc*BC + c);
        }
        __syncthreads();

        // S = Q.K^T (scale folded into q): 4 key-groups x 2 d-halves
        floatx4 Sf[4];
#pragma unroll
        for (int kg = 0; kg < 4; ++kg) {
            floatx4 a;
#pragma unroll
            for (int r = 0; r < 4; ++r) a[r] = 0.f;
            half8 kb0 = *(half8*)&Ks[kg*16 + l][quad*8];
            half8 kb1 = *(half8*)&Ks[kg*16 + l][quad*8 + 32];
            a = __builtin_amdgcn_mfma_f32_16x16x32_f16(qf0, kb0, a, 0, 0, 0);
            a = __builtin_amdgcn_mfma_f32_16x16x32_f16(qf1, kb1, a, 0, 0, 0);
            Sf[kg] = a;
        }

        // online softmax; lane holds rows q = quad*4 + r across 16-lane key cols
        float mloc[4], lloc[4], alpha[4];
#pragma unroll
        for (int r = 0; r < 4; ++r)
            mloc[r] = fmaxf(fmaxf(Sf[0][r], Sf[1][r]), fmaxf(Sf[2][r], Sf[3][r]));
#pragma unroll
        for (int m = 1; m <= 8; m <<= 1)
#pragma unroll
            for (int r = 0; r < 4; ++r)
                mloc[r] = fmaxf(mloc[r], __shfl_xor(mloc[r], m));
#pragma unroll
        for (int r = 0; r < 4; ++r) {
            float mn = fmaxf(mrow[r], mloc[r]);
            alpha[r] = exp2f((mrow[r] - mn)*LOG2E);
            mrow[r]  = mn;
        }
#pragma unroll
        for (int r = 0; r < 4; ++r) lloc[r] = 0.f;
#pragma unroll
        for (int kg = 0; kg < 4; ++kg)
#pragma unroll
            for (int r = 0; r < 4; ++r) {
                float p = exp2f((Sf[kg][r] - mrow[r])*LOG2E);
                Sf[kg][r] = p;
                lloc[r] += p;
            }
#pragma unroll
        for (int m = 1; m <= 8; m <<= 1)
#pragma unroll
            for (int r = 0; r < 4; ++r)
                lloc[r] += __shfl_xor(lloc[r], m);
#pragma unroll
        for (int r = 0; r < 4; ++r) lrow[r] = lrow[r]*alpha[r] + lloc[r];

        // P round-trip: C-layout -> LDS -> A-layout (m120)
#pragma unroll
        for (int kg = 0; kg < 4; ++kg)
#pragma unroll
            for (int r = 0; r < 4; ++r)
                Ps[w][quad*4 + r][l + 16*kg] = (_Float16)Sf[kg][r];

        // rescale O by alpha
#pragma unroll
        for (int dt = 0; dt < 4; ++dt)
#pragma unroll
            for (int r = 0; r < 4; ++r) Of[dt][r] *= alpha[r];

        half8 pa0 = *(half8*)&Ps[w][l][quad*8];
        half8 pa1 = *(half8*)&Ps[w][l][quad*8 + 32];
#pragma unroll
        for (int dt = 0; dt < 4; ++dt) {
            half8 vb0 = *(half8*)&Vs[dt*16 + l][quad*8];
            half8 vb1 = *(half8*)&Vs[dt*16 + l][quad*8 + 32];
            Of[dt] = __builtin_amdgcn_mfma_f32_16x16x32_f16(pa0, vb0, Of[dt], 0, 0, 0);
            Of[dt] = __builtin_amdgcn_mfma_f32_16x16x32_f16(pa1, vb1, Of[dt], 0, 0, 0);
        }
    }

    // epilogue: O[q][d] row = quad*4+r, col = dt*16+l; divide by l, store fp32
    float inv[4];
#pragma unroll
    for (int r = 0; r < 4; ++r) inv[r] = 1.0f / lrow[r];
#pragma unroll
    for (int dt = 0; dt < 4; ++dt)
#pragma unroll
        for (int r = 0; r < 4; ++r)
            op[(size_t)(w*16 + quad*4 + r)*DH + dt*16 + l] = Of[dt][r]*inv[r];
}

// ---------------------------------------------------------------------------
// GEMM2: out = o(8192x1024, gathered from [bt][head][s][dim]) @ Wout + bout
// ---------------------------------------------------------------------------
__global__ __launch_bounds__(256) void gemm_out(
    const float* __restrict__ ow, const float* __restrict__ Wo,
    const float* __restrict__ bo, float* __restrict__ out)
{
    __shared__ float As[16][128];
    __shared__ float Bs[16][128];
    const int bx = blockIdx.x;   // 0..7
    const int by = blockIdx.y;   // 0..63
    const int tid = threadIdx.x;
    const int tx = tid & 15, ty = tid >> 4;
    const int ar = tid >> 1;
    const int ak = (tid & 1) * 8;
    const int brow = tid >> 4;
    const int bcol = (tid & 15) * 8;

    const int r  = by*128 + ar;
    const int bt = r >> 10, s = r & 1023;
    const float* Abase = ow + (size_t)bt*NH*HS + (size_t)s*DH;
    const float* Bp = Wo + (size_t)brow*DMODEL + bx*128 + bcol;

    float acc[8][8];
#pragma unroll
    for (int i = 0; i < 8; ++i)
#pragma unroll
        for (int j = 0; j < 8; ++j) acc[i][j] = 0.f;

    for (int k0 = 0; k0 < DMODEL; k0 += 16) {
        int k = k0 + ak;                        // 8-aligned, stays in one head block
        const float* ap = Abase + (size_t)(k >> 6)*HS + (k & 63);
        float4 a0 = *(const float4*)ap;
        float4 a1 = *(const float4*)(ap + 4);
        float4 b0 = *(const float4*)(Bp + (size_t)k0*DMODEL);
        float4 b1 = *(const float4*)(Bp + (size_t)k0*DMODEL + 4);
        __syncthreads();
        As[ak+0][ar] = a0.x; As[ak+1][ar] = a0.y; As[ak+2][ar] = a0.z; As[ak+3][ar] = a0.w;
        As[ak+4][ar] = a1.x; As[ak+5][ar] = a1.y; As[ak+6][ar] = a1.z; As[ak+7][ar] = a1.w;
        *(float4*)&Bs[brow][bcol]   = b0;
        *(float4*)&Bs[brow][bcol+4] = b1;
        __syncthreads();
#pragma unroll
        for (int kk = 0; kk < 16; ++kk) {
            float av[8], bv[8];
            *(float4*)&av[0] = *(float4*)&As[kk][ty*8];
            *(float4*)&av[4] = *(float4*)&As[kk][ty*8+4];
            *(float4*)&bv[0] = *(float4*)&Bs[kk][tx*8];
            *(float4*)&bv[4] = *(float4*)&Bs[kk][tx*8+4];
#pragma unroll
            for (int i = 0; i < 8; ++i)
#pragma unroll
                for (int j = 0; j < 8; ++j)
                    acc[i][j] += av[i]*bv[j];
        }
    }

    const int cb = bx*128 + tx*8;
    float4 bias0 = *(const float4*)(bo + cb);
    float4 bias1 = *(const float4*)(bo + cb + 4);
#pragma unroll
    for (int i = 0; i < 8; ++i) {
        int row = by*128 + ty*8 + i;
        float4 o0, o1;
        o0.x = acc[i][0] + bias0.x; o0.y = acc[i][1] + bias0.y;
        o0.z = acc[i][2] + bias0.z; o0.w = acc[i][3] + bias0.w;
        o1.x = acc[i][4] + bias1.x; o1.y = acc[i][5] + bias1.y;
        o1.z = acc[i][6] + bias1.z; o1.w = acc[i][7] + bias1.w;
        float* dst = out + (size_t)row*DMODEL + cb;
        *(float4*)dst     = o0;
        *(float4*)(dst+4) = o1;
    }
}

// ---------------------------------------------------------------------------
extern "C" void kernel_launch(void* const* d_in, const int* in_sizes, int n_in,
                              void* d_out, int out_size, void* d_ws, size_t ws_size,
                              hipStream_t stream)
{
    const float* x    = (const float*)d_in[0];
    const float* Wqkv = (const float*)d_in[1];
    const float* Wout = (const float*)d_in[2];
    const float* bout = (const float*)d_in[3];
    float* out = (float*)d_out;

    _Float16* qw = (_Float16*)d_ws;                 // 8*16*1024*64 = 8388608 f16
    _Float16* kw = qw + 8388608;
    _Float16* vt = kw + 8388608;                    // transposed [bh][d][s]
    float*    ow = (float*)(vt + 8388608);          // fp32, 8388608 floats

    hipLaunchKernelGGL(gemm_qkv_rope, dim3(24, 64), dim3(256), 0, stream,
                       x, Wqkv, qw, kw, vt);
    hipLaunchKernelGGL(attn_mfma, dim3(16, 128), dim3(256), 0, stream,
                       qw, kw, vt, ow);
    hipLaunchKernelGGL(gemm_out, dim3(8, 64), dim3(256), 0, stream,
                       ow, Wout, bout, out);
}

// Round 3
// 351.829 us; speedup vs baseline: 4.6885x; 2.7756x over previous
//
#include <hip/hip_runtime.h>
#include <math.h>

#define DMODEL 1024
#define NQKV   3072
#define SEQ    1024
#define NH     16
#define DH     64
#define HS     (SEQ*DH)
constexpr float PI_F   = 3.14159265358979323846f;
constexpr float LOG2E  = 1.44269504088896f;

typedef _Float16 half8   __attribute__((ext_vector_type(8)));
typedef float    floatx4 __attribute__((ext_vector_type(4)));

// async global->LDS, 16B per lane; LDS dest is wave-uniform base + lane*16
__device__ __forceinline__ void gload_lds16(const _Float16* g, _Float16* l) {
    __builtin_amdgcn_global_load_lds(
        (const __attribute__((address_space(1))) unsigned int*)g,
        (__attribute__((address_space(3)))       unsigned int*)l,
        16, 0, 0);
}

// ---------------------------------------------------------------------------
// flat fp32 -> f16 convert
// ---------------------------------------------------------------------------
__global__ __launch_bounds__(256) void cvt_f16(
    const float* __restrict__ in, _Float16* __restrict__ out, int n)
{
    int i = (blockIdx.x*256 + threadIdx.x)*8;
    if (i >= n) return;
    float4 a = *(const float4*)(in + i);
    float4 b = *(const float4*)(in + i + 4);
    half8 h;
    h[0]=(_Float16)a.x; h[1]=(_Float16)a.y; h[2]=(_Float16)a.z; h[3]=(_Float16)a.w;
    h[4]=(_Float16)b.x; h[5]=(_Float16)b.y; h[6]=(_Float16)b.z; h[7]=(_Float16)b.w;
    *(half8*)(out + i) = h;
}

// ---------------------------------------------------------------------------
// transpose + convert: in [R][C] fp32 -> out [C][R] f16   (32x32 tiles)
// ---------------------------------------------------------------------------
__global__ __launch_bounds__(256) void tr_cvt(
    const float* __restrict__ in, _Float16* __restrict__ out, int R, int C)
{
    __shared__ float T[32][33];
    const int bx = blockIdx.x, by = blockIdx.y;
    const int tx = threadIdx.x & 31, ty = threadIdx.x >> 5;
#pragma unroll
    for (int i = 0; i < 4; ++i)
        T[ty + i*8][tx] = in[(size_t)(by*32 + ty + i*8)*C + bx*32 + tx];
    __syncthreads();
#pragma unroll
    for (int i = 0; i < 4; ++i)
        out[(size_t)(bx*32 + ty + i*8)*R + by*32 + tx] = (_Float16)T[tx][ty + i*8];
}

// ---------------------------------------------------------------------------
// m97-style f16 GEMM core: C[M][N] = A[M][K] @ Bt[N][K]^T
// 128x128 tile, BK=32, 4 waves (2x2), 4x4 16x16x32 MFMAs per wave.
// ---------------------------------------------------------------------------
__global__ __launch_bounds__(256) void gemm1_f16(
    const _Float16* __restrict__ A, const _Float16* __restrict__ Bt,
    _Float16* __restrict__ C, int M, int N, int K)
{
    __shared__ _Float16 As[128*32];
    __shared__ _Float16 Bs[128*32];
    const int tid = threadIdx.x;
    const int w = tid >> 6, lane = tid & 63, quad = lane >> 4, l = lane & 15;
    const int wm = (w & 1)*64, wn = (w >> 1)*64;
    const int m0 = blockIdx.y*128, n0 = blockIdx.x*128;

    const _Float16* a0 = A  + (size_t)(m0 + w*32      + (lane>>2))*K + (lane&3)*8;
    const _Float16* a1 = A  + (size_t)(m0 + w*32 + 16 + (lane>>2))*K + (lane&3)*8;
    const _Float16* b0 = Bt + (size_t)(n0 + w*32      + (lane>>2))*K + (lane&3)*8;
    const _Float16* b1 = Bt + (size_t)(n0 + w*32 + 16 + (lane>>2))*K + (lane&3)*8;
    _Float16* lA0 = As + w*1024;
    _Float16* lA1 = As + w*1024 + 512;
    _Float16* lB0 = Bs + w*1024;
    _Float16* lB1 = Bs + w*1024 + 512;

    floatx4 acc[4][4];
#pragma unroll
    for (int i = 0; i < 4; ++i)
#pragma unroll
        for (int j = 0; j < 4; ++j)
#pragma unroll
            for (int r = 0; r < 4; ++r) acc[i][j][r] = 0.f;

    for (int k0 = 0; k0 < K; k0 += 32) {
        __syncthreads();
        gload_lds16(a0, lA0); gload_lds16(a1, lA1);
        gload_lds16(b0, lB0); gload_lds16(b1, lB1);
        a0 += 32; a1 += 32; b0 += 32; b1 += 32;
        __syncthreads();
        half8 bf[4];
#pragma unroll
        for (int nt = 0; nt < 4; ++nt)
            bf[nt] = *(half8*)&Bs[(wn + nt*16 + l)*32 + quad*8];
#pragma unroll
        for (int mt = 0; mt < 4; ++mt) {
            half8 af = *(half8*)&As[(wm + mt*16 + l)*32 + quad*8];
#pragma unroll
            for (int nt = 0; nt < 4; ++nt)
                acc[mt][nt] = __builtin_amdgcn_mfma_f32_16x16x32_f16(af, bf[nt], acc[mt][nt], 0, 0, 0);
        }
    }
    // epilogue: C/D row = quad*4+r (m), col = l (n); f16 store
#pragma unroll
    for (int mt = 0; mt < 4; ++mt)
#pragma unroll
        for (int r = 0; r < 4; ++r) {
            size_t row = m0 + wm + mt*16 + quad*4 + r;
#pragma unroll
            for (int nt = 0; nt < 4; ++nt)
                C[row*N + n0 + wn + nt*16 + l] = (_Float16)acc[mt][nt][r];
        }
}

// same core, fp32 output + bias
__global__ __launch_bounds__(256) void gemm2_f16(
    const _Float16* __restrict__ A, const _Float16* __restrict__ Bt,
    const float* __restrict__ bias, float* __restrict__ C, int M, int N, int K)
{
    __shared__ _Float16 As[128*32];
    __shared__ _Float16 Bs[128*32];
    const int tid = threadIdx.x;
    const int w = tid >> 6, lane = tid & 63, quad = lane >> 4, l = lane & 15;
    const int wm = (w & 1)*64, wn = (w >> 1)*64;
    const int m0 = blockIdx.y*128, n0 = blockIdx.x*128;

    const _Float16* a0 = A  + (size_t)(m0 + w*32      + (lane>>2))*K + (lane&3)*8;
    const _Float16* a1 = A  + (size_t)(m0 + w*32 + 16 + (lane>>2))*K + (lane&3)*8;
    const _Float16* b0 = Bt + (size_t)(n0 + w*32      + (lane>>2))*K + (lane&3)*8;
    const _Float16* b1 = Bt + (size_t)(n0 + w*32 + 16 + (lane>>2))*K + (lane&3)*8;
    _Float16* lA0 = As + w*1024;
    _Float16* lA1 = As + w*1024 + 512;
    _Float16* lB0 = Bs + w*1024;
    _Float16* lB1 = Bs + w*1024 + 512;

    floatx4 acc[4][4];
#pragma unroll
    for (int i = 0; i < 4; ++i)
#pragma unroll
        for (int j = 0; j < 4; ++j)
#pragma unroll
            for (int r = 0; r < 4; ++r) acc[i][j][r] = 0.f;

    for (int k0 = 0; k0 < K; k0 += 32) {
        __syncthreads();
        gload_lds16(a0, lA0); gload_lds16(a1, lA1);
        gload_lds16(b0, lB0); gload_lds16(b1, lB1);
        a0 += 32; a1 += 32; b0 += 32; b1 += 32;
        __syncthreads();
        half8 bf[4];
#pragma unroll
        for (int nt = 0; nt < 4; ++nt)
            bf[nt] = *(half8*)&Bs[(wn + nt*16 + l)*32 + quad*8];
#pragma unroll
        for (int mt = 0; mt < 4; ++mt) {
            half8 af = *(half8*)&As[(wm + mt*16 + l)*32 + quad*8];
#pragma unroll
            for (int nt = 0; nt < 4; ++nt)
                acc[mt][nt] = __builtin_amdgcn_mfma_f32_16x16x32_f16(af, bf[nt], acc[mt][nt], 0, 0, 0);
        }
    }
#pragma unroll
    for (int mt = 0; mt < 4; ++mt)
#pragma unroll
        for (int r = 0; r < 4; ++r) {
            size_t row = m0 + wm + mt*16 + quad*4 + r;
#pragma unroll
            for (int nt = 0; nt < 4; ++nt) {
                int col = n0 + wn + nt*16 + l;
                C[row*N + col] = acc[mt][nt][r] + bias[col];
            }
        }
}

// ---------------------------------------------------------------------------
// rope + scatter: qkv_tmp[8192][3072] f16 -> qw/kw [bh][s][64] (q pre-scaled
// 1/8), vt [bh][d][1024] (transposed). Block = one (bh, 64-s chunk).
// ---------------------------------------------------------------------------
__global__ __launch_bounds__(256) void rope_scatter(
    const _Float16* __restrict__ qkv,
    _Float16* __restrict__ qw, _Float16* __restrict__ kw,
    _Float16* __restrict__ vt)
{
    const int sc = blockIdx.x;       // 0..15
    const int bh = blockIdx.y;       // 0..127
    const int bt = bh >> 4, head = bh & 15;
    const int s0 = sc*64;
    const int tid = threadIdx.x;
    const int d0 = (tid & 7)*8;

    __shared__ _Float16 T[64][80];   // v transpose staging

#pragma unroll
    for (int half = 0; half < 2; ++half) {
        const int r = (tid >> 3) + half*32;
        const int s = s0 + r;
        const _Float16* src = qkv + (size_t)(bt*SEQ + s)*NQKV + head*DH + d0;
        half8 hq = *(const half8*)(src);
        half8 hk = *(const half8*)(src + DMODEL);
        half8 hv = *(const half8*)(src + 2*DMODEL);
        float fq[8], fk[8];
#pragma unroll
        for (int j = 0; j < 8; ++j) { fq[j] = (float)hq[j]; fk[j] = (float)hk[j]; }
        const int hp = s >> 5, wp = s & 31;
        const float ph = -1.0f + hp*(2.0f/31.0f);
        const float pw = -1.0f + wp*(2.0f/31.0f);
#pragma unroll
        for (int p = 0; p < 4; ++p) {
            int pg = (d0 >> 1) + p;
            float pos = (pg < 16) ? ph : pw;
            int   gi  = (pg < 16) ? pg : (pg - 16);
            float th  = pos * ((1.0f + gi*(127.0f/15.0f)) * PI_F);
            float sn, cs;
            sincosf(th, &sn, &cs);
            float q1 = fq[2*p], q2 = fq[2*p+1];
            fq[2*p]   = q1*cs - q2*sn;
            fq[2*p+1] = q2*cs + q1*sn;
            float k1 = fk[2*p], k2 = fk[2*p+1];
            fk[2*p]   = k1*cs - k2*sn;
            fk[2*p+1] = k2*cs + k1*sn;
        }
        half8 oq, ok;
#pragma unroll
        for (int j = 0; j < 8; ++j) {
            oq[j] = (_Float16)(fq[j]*0.125f);
            ok[j] = (_Float16)fk[j];
        }
        *(half8*)(qw + (size_t)bh*HS + (size_t)s*DH + d0) = oq;
        *(half8*)(kw + (size_t)bh*HS + (size_t)s*DH + d0) = ok;
#pragma unroll
        for (int j = 0; j < 8; ++j) T[d0 + j][r] = hv[j];
    }
    __syncthreads();
    const int d = tid >> 2, so = (tid & 3)*16;
    half8 v0 = *(half8*)&T[d][so];
    half8 v1 = *(half8*)&T[d][so + 8];
    _Float16* dst = vt + (size_t)bh*HS + (size_t)d*SEQ + s0 + so;
    *(half8*)dst       = v0;
    *(half8*)(dst + 8) = v1;
}

// ---------------------------------------------------------------------------
// Flash attention, f16 MFMA (round-2 verified); epilogue stores f16 o
// row-major [bt*1024+s][head*64+d] to feed gemm2 directly.
// ---------------------------------------------------------------------------
#define BQ  64
#define BC  64
#define LDH 72

__global__ __launch_bounds__(256) void attn_mfma(
    const _Float16* __restrict__ qw, const _Float16* __restrict__ kw,
    const _Float16* __restrict__ vt, _Float16* __restrict__ om)
{
    const int qc = blockIdx.x;
    const int bh = blockIdx.y;
    const _Float16* qp = qw + (size_t)bh*HS + qc*BQ*DH;
    const _Float16* kp = kw + (size_t)bh*HS;
    const _Float16* vp = vt + (size_t)bh*HS;

    __shared__ _Float16 Qs[BQ][LDH];
    __shared__ _Float16 Ks[BC][LDH];
    __shared__ _Float16 Vs[DH][LDH];
    __shared__ _Float16 Ps[4][16][LDH];

    const int tid  = threadIdx.x;
    const int w    = tid >> 6;
    const int lane = tid & 63;
    const int quad = lane >> 4;
    const int l    = lane & 15;

    for (int idx = tid; idx < BQ*8; idx += 256) {
        int r = idx >> 3, c = (idx & 7)*8;
        *(half8*)&Qs[r][c] = *(const half8*)(qp + (size_t)r*DH + c);
    }
    __syncthreads();
    half8 qf0 = *(half8*)&Qs[w*16 + l][quad*8];
    half8 qf1 = *(half8*)&Qs[w*16 + l][quad*8 + 32];

    floatx4 Of[4];
    float mrow[4], lrow[4];
#pragma unroll
    for (int dt = 0; dt < 4; ++dt)
#pragma unroll
        for (int r = 0; r < 4; ++r) Of[dt][r] = 0.f;
#pragma unroll
    for (int r = 0; r < 4; ++r) { mrow[r] = -INFINITY; lrow[r] = 0.f; }

    for (int kc = 0; kc < SEQ/BC; ++kc) {
        __syncthreads();
        for (int idx = tid; idx < BC*8; idx += 256) {
            int r = idx >> 3, c = (idx & 7)*8;
            *(half8*)&Ks[r][c] = *(const half8*)(kp + (size_t)(kc*BC + r)*DH + c);
        }
        for (int idx = tid; idx < DH*8; idx += 256) {
            int r = idx >> 3, c = (idx & 7)*8;
            *(half8*)&Vs[r][c] = *(const half8*)(vp + (size_t)r*SEQ + kc*BC + c);
        }
        __syncthreads();

        floatx4 Sf[4];
#pragma unroll
        for (int kg = 0; kg < 4; ++kg) {
            floatx4 a;
#pragma unroll
            for (int r = 0; r < 4; ++r) a[r] = 0.f;
            half8 kb0 = *(half8*)&Ks[kg*16 + l][quad*8];
            half8 kb1 = *(half8*)&Ks[kg*16 + l][quad*8 + 32];
            a = __builtin_amdgcn_mfma_f32_16x16x32_f16(qf0, kb0, a, 0, 0, 0);
            a = __builtin_amdgcn_mfma_f32_16x16x32_f16(qf1, kb1, a, 0, 0, 0);
            Sf[kg] = a;
        }

        float mloc[4], lloc[4], alpha[4];
#pragma unroll
        for (int r = 0; r < 4; ++r)
            mloc[r] = fmaxf(fmaxf(Sf[0][r], Sf[1][r]), fmaxf(Sf[2][r], Sf[3][r]));
#pragma unroll
        for (int m = 1; m <= 8; m <<= 1)
#pragma unroll
            for (int r = 0; r < 4; ++r)
                mloc[r] = fmaxf(mloc[r], __shfl_xor(mloc[r], m));
#pragma unroll
        for (int r = 0; r < 4; ++r) {
            float mn = fmaxf(mrow[r], mloc[r]);
            alpha[r] = exp2f((mrow[r] - mn)*LOG2E);
            mrow[r]  = mn;
        }
#pragma unroll
        for (int r = 0; r < 4; ++r) lloc[r] = 0.f;
#pragma unroll
        for (int kg = 0; kg < 4; ++kg)
#pragma unroll
            for (int r = 0; r < 4; ++r) {
                float p = exp2f((Sf[kg][r] - mrow[r])*LOG2E);
                Sf[kg][r] = p;
                lloc[r] += p;
            }
#pragma unroll
        for (int m = 1; m <= 8; m <<= 1)
#pragma unroll
            for (int r = 0; r < 4; ++r)
                lloc[r] += __shfl_xor(lloc[r], m);
#pragma unroll
        for (int r = 0; r < 4; ++r) lrow[r] = lrow[r]*alpha[r] + lloc[r];

#pragma unroll
        for (int kg = 0; kg < 4; ++kg)
#pragma unroll
            for (int r = 0; r < 4; ++r)
                Ps[w][quad*4 + r][l + 16*kg] = (_Float16)Sf[kg][r];

#pragma unroll
        for (int dt = 0; dt < 4; ++dt)
#pragma unroll
            for (int r = 0; r < 4; ++r) Of[dt][r] *= alpha[r];

        half8 pa0 = *(half8*)&Ps[w][l][quad*8];
        half8 pa1 = *(half8*)&Ps[w][l][quad*8 + 32];
#pragma unroll
        for (int dt = 0; dt < 4; ++dt) {
            half8 vb0 = *(half8*)&Vs[dt*16 + l][quad*8];
            half8 vb1 = *(half8*)&Vs[dt*16 + l][quad*8 + 32];
            Of[dt] = __builtin_amdgcn_mfma_f32_16x16x32_f16(pa0, vb0, Of[dt], 0, 0, 0);
            Of[dt] = __builtin_amdgcn_mfma_f32_16x16x32_f16(pa1, vb1, Of[dt], 0, 0, 0);
        }
    }

    const int bt = bh >> 4, head = bh & 15;
    _Float16* opf = om + (size_t)(bt*SEQ + qc*BQ)*DMODEL + head*DH;
    float inv[4];
#pragma unroll
    for (int r = 0; r < 4; ++r) inv[r] = 1.0f / lrow[r];
#pragma unroll
    for (int dt = 0; dt < 4; ++dt)
#pragma unroll
        for (int r = 0; r < 4; ++r)
            opf[(size_t)(w*16 + quad*4 + r)*DMODEL + dt*16 + l] =
                (_Float16)(Of[dt][r]*inv[r]);
}

// ---------------------------------------------------------------------------
extern "C" void kernel_launch(void* const* d_in, const int* in_sizes, int n_in,
                              void* d_out, int out_size, void* d_ws, size_t ws_size,
                              hipStream_t stream)
{
    const float* x    = (const float*)d_in[0];
    const float* Wqkv = (const float*)d_in[1];
    const float* Wout = (const float*)d_in[2];
    const float* bout = (const float*)d_in[3];
    float* out = (float*)d_out;

    _Float16* ws   = (_Float16*)d_ws;
    _Float16* Xh   = ws;                  // 8388608
    _Float16* Wqkt = ws + 8388608;        // 3145728  [3072][1024]
    _Float16* Wot  = ws + 11534336;       // 1048576  [1024][1024]
    _Float16* qkvt = ws + 12582912;       // 25165824 [8192][3072]
    _Float16* qw   = ws + 37748736;       // 8388608
    _Float16* kw   = ws + 46137344;       // 8388608
    _Float16* vt   = ws + 54525952;       // 8388608  (end: 120 MiB)
    _Float16* om   = qkvt;                // alias: reused after rope_scatter

    hipLaunchKernelGGL(cvt_f16, dim3(4096), dim3(256), 0, stream,
                       x, Xh, 8388608);
    hipLaunchKernelGGL(tr_cvt, dim3(96, 32), dim3(256), 0, stream,
                       Wqkv, Wqkt, 1024, 3072);
    hipLaunchKernelGGL(tr_cvt, dim3(32, 32), dim3(256), 0, stream,
                       Wout, Wot, 1024, 1024);
    hipLaunchKernelGGL(gemm1_f16, dim3(24, 64), dim3(256), 0, stream,
                       Xh, Wqkt, qkvt, 8192, NQKV, DMODEL);
    hipLaunchKernelGGL(rope_scatter, dim3(16, 128), dim3(256), 0, stream,
                       qkvt, qw, kw, vt);
    hipLaunchKernelGGL(attn_mfma, dim3(16, 128), dim3(256), 0, stream,
                       qw, kw, vt, om);
    hipLaunchKernelGGL(gemm2_f16, dim3(8, 64), dim3(256), 0, stream,
                       om, Wot, bout, out, 8192, DMODEL, DMODEL);
}